// Round 6
// baseline (176.894 us; speedup 1.0000x reference)
//
#include <hip/hip_runtime.h>
#include <hip/hip_bf16.h>
#include <cstddef>

typedef __attribute__((ext_vector_type(8))) short short8;
typedef __attribute__((ext_vector_type(4))) float f32x4;
typedef __attribute__((ext_vector_type(16))) float f32x16;
typedef __attribute__((ext_vector_type(4))) unsigned short u16x4;

#define D_MODEL 768
#define N_HEADS 4
#define HEAD_DIM 192
#define BATCH 4
#define SEQ 2048
#define M_ROWS (BATCH*SEQ)

__device__ __forceinline__ short f2bf(float f) {
  union { float f; unsigned u; } v; v.f = f;
  unsigned r = v.u + 0x7FFFu + ((v.u >> 16) & 1u);
  return (short)(r >> 16);
}

__device__ __forceinline__ float fexp2(float x) {
  return __builtin_amdgcn_exp2f(x);
}

__device__ __forceinline__ void gl_lds16(const void* g, void* l) {
  __builtin_amdgcn_global_load_lds(
      (const __attribute__((address_space(1))) void*)g,
      (__attribute__((address_space(3))) void*)l, 16, 0, 0);
}

// ---------------- cast fp32 -> bf16, 8 elems/thread ----------------
__global__ __launch_bounds__(256) void cast_kernel(const float* __restrict__ src,
                                                   short* __restrict__ dst, int n8) {
  int i = blockIdx.x * 256 + threadIdx.x;
  if (i >= n8) return;
  const float4* s = (const float4*)src;
  float4 a = s[2 * i], b = s[2 * i + 1];
  short8 o;
  o[0] = f2bf(a.x); o[1] = f2bf(a.y); o[2] = f2bf(a.z); o[3] = f2bf(a.w);
  o[4] = f2bf(b.x); o[5] = f2bf(b.y); o[6] = f2bf(b.z); o[7] = f2bf(b.w);
  *(short8*)(dst + (size_t)i * 8) = o;
}

// ---------------- transpose-cast W[k][n] f32 -> Wt[n][k] bf16 ----------------
__global__ __launch_bounds__(256) void wtrans(const float* __restrict__ W,
                                              short* __restrict__ Wt) {
  __shared__ float tile[32][33];
  int k0 = blockIdx.x * 32, n0 = blockIdx.y * 32;
  int tc = threadIdx.x & 31, tr = threadIdx.x >> 5;
#pragma unroll
  for (int i = 0; i < 4; i++)
    tile[tr + i * 8][tc] = W[(size_t)(k0 + tr + i * 8) * D_MODEL + n0 + tc];
  __syncthreads();
#pragma unroll
  for (int i = 0; i < 4; i++)
    Wt[(size_t)(n0 + tr + i * 8) * D_MODEL + k0 + tc] = f2bf(tile[tc][tr + i * 8]);
}

__global__ __launch_bounds__(256) void bias_concat(const float* __restrict__ a,
                                                   const float* __restrict__ b,
                                                   const float* __restrict__ c,
                                                   float* __restrict__ dst) {
  int i = blockIdx.x * 256 + threadIdx.x;
  if (i >= 3 * D_MODEL) return;
  float v = i < 768 ? a[i] : (i < 1536 ? b[i - 768] : c[i - 1536]);
  dst[i] = v;
}

// ---------------- bf16 MFMA GEMM, 128x128 tile, BK=64, global_load_lds ----------------
template <int MODE>
__global__ __launch_bounds__(256, 4) void gemm_bf16(const short* __restrict__ A,
                                                    const short* __restrict__ Wt,
                                                    const float* __restrict__ bias,
                                                    short* __restrict__ oQ,
                                                    short* __restrict__ oK,
                                                    short* __restrict__ oV,
                                                    float* __restrict__ oF, int N) {
  __shared__ short As[128 * 64];
  __shared__ short Bs[128 * 64];
  const int K = 768;
  const int m0 = blockIdx.x * 128, n0 = blockIdx.y * 128;
  const int t = threadIdx.x, lane = t & 63, w = t >> 6;
  const int wr = w >> 1, wc = w & 1, lr = lane & 15, lg = lane >> 4;

  f32x4 acc[4][4] = {};

  for (int k0 = 0; k0 < K; k0 += 64) {
#pragma unroll
    for (int i = 0; i < 4; i++) {
      int id = w * 4 + i;
      int row = id * 8 + (lane >> 3);
      int cc = (lane & 7) ^ (row & 7);
      gl_lds16(A + (size_t)(m0 + row) * K + k0 + cc * 8, As + id * 512);
      gl_lds16(Wt + (size_t)(n0 + row) * K + k0 + cc * 8, Bs + id * 512);
    }
    __syncthreads();
#pragma unroll
    for (int kb = 0; kb < 2; kb++) {
      short8 a[4], b[4];
#pragma unroll
      for (int m = 0; m < 4; m++) {
        int row = wr * 64 + m * 16 + lr;
        a[m] = *(const short8*)&As[row * 64 + (((kb * 4 + lg) ^ (row & 7)) << 3)];
      }
#pragma unroll
      for (int n = 0; n < 4; n++) {
        int row = wc * 64 + n * 16 + lr;
        b[n] = *(const short8*)&Bs[row * 64 + (((kb * 4 + lg) ^ (row & 7)) << 3)];
      }
#pragma unroll
      for (int m = 0; m < 4; m++)
#pragma unroll
        for (int n = 0; n < 4; n++)
          acc[m][n] = __builtin_amdgcn_mfma_f32_16x16x32_bf16(a[m], b[n], acc[m][n], 0, 0, 0);
    }
    __syncthreads();
  }

  if (MODE == 0) {
#pragma unroll
    for (int m = 0; m < 4; m++)
#pragma unroll
      for (int n = 0; n < 4; n++) {
        int col = n0 + wc * 64 + n * 16 + lr;
        float bv = bias[col];
#pragma unroll
        for (int r = 0; r < 4; r++) {
          int row = m0 + wr * 64 + m * 16 + lg * 4 + r;
          oF[(size_t)row * N + col] = acc[m][n][r] + bv;
        }
      }
  } else {
    const int bb = m0 >> 11;
#pragma unroll
    for (int m = 0; m < 4; m++) {
      int s0 = (m0 & (SEQ - 1)) + wr * 64 + m * 16 + lg * 4;
#pragma unroll
      for (int n = 0; n < 4; n++) {
        int col = n0 + wc * 64 + n * 16 + lr;
        int seg = col / 768;
        int d = col - seg * 768;
        int h = d / HEAD_DIM, dd = d - h * HEAD_DIM;
        int bh = bb * N_HEADS + h;
        float bv = bias[col];
        if (seg < 2) {
          short* dst = seg == 0 ? oQ : oK;
#pragma unroll
          for (int r = 0; r < 4; r++)
            dst[((size_t)bh * SEQ + s0 + r) * HEAD_DIM + dd] = f2bf(acc[m][n][r] + bv);
        } else {
          u16x4 pk;
#pragma unroll
          for (int r = 0; r < 4; r++) pk[r] = (unsigned short)f2bf(acc[m][n][r] + bv);
          *(u16x4*)&oV[((size_t)bh * HEAD_DIM + dd) * SEQ + s0] = pk;
        }
      }
    }
  }
}

// ---------------- attention staging: global -> regs, regs -> LDS ----------------
__device__ __forceinline__ void load_kv_regs(const short* Kp, const short* Vp, int kbase,
                                             int w, int lane, short8* kr, short8* vr) {
#pragma unroll
  for (int i = 0; i < 6; i++) {
    int o16 = (w * 6 + i) * 64 + lane;
    int row = o16 / 24, cc = (o16 - row * 24) ^ (row & 7);
    kr[i] = *(const short8*)&Kp[(size_t)(kbase + row) * HEAD_DIM + cc * 8];
    int vrow = o16 >> 3, vcc = (o16 & 7) ^ (vrow & 7);
    vr[i] = *(const short8*)&Vp[(size_t)vrow * SEQ + kbase + vcc * 8];
  }
}

__device__ __forceinline__ void write_kv_lds(short* Ks, short* Vs, int w, int lane,
                                             const short8* kr, const short8* vr) {
#pragma unroll
  for (int i = 0; i < 6; i++) {
    int o16 = (w * 6 + i) * 64 + lane;
    *(short8*)&Ks[o16 * 8] = kr[i];
    *(short8*)&Vs[o16 * 8] = vr[i];
  }
}

// ---------------- flash causal attention: 32x32 frags, swapped QK^T ----------------
// 512 blocks (one q-tile of 64 rows each), 4 waves = 2 q-split x 2 k-split.
// Single-buffered K/V LDS (48KB) + reg-staged prefetch (T14) -> 2 blocks/CU.
// Q,K: [bh][s][192]; V: [bh][192][s]; ctx: bf16 [b][s][768]
__global__ __launch_bounds__(256, 2) void attn_kernel(const short* __restrict__ Q,
                                                      const short* __restrict__ Kg,
                                                      const short* __restrict__ Vt,
                                                      short* __restrict__ ctx) {
  __shared__ short smem[64 * 192 + 192 * 64];  // K tile | V tile (49152 B)
  __shared__ float mlbuf[128];
  short* Ks = smem;
  short* Vs = smem + 64 * 192;
  float* obuf = (float*)smem;  // merge buffer, reuses K+V region after k-loop

  // LPT pairing: first 256 blocks get qt 31..16, second 256 get qt 0..15
  const int i = blockIdx.x;
  int bh, qt;
  if (i < 256) { bh = i & 15; qt = 31 - (i >> 4); }
  else         { int j = i - 256; bh = j & 15; qt = j >> 4; }

  const int b = bh >> 2, head = bh & 3;
  const short* Qp = Q + (size_t)bh * SEQ * HEAD_DIM;
  const short* Kp = Kg + (size_t)bh * SEQ * HEAD_DIM;
  const short* Vp = Vt + (size_t)bh * HEAD_DIM * SEQ;
  const int t = threadIdx.x, lane = t & 63, w = t >> 6;
  const int wq = w >> 1, wk = w & 1;
  const int l31 = lane & 31, hl = lane >> 5;
  const float scale2 = 0.07216878364870322f * 1.4426950408889634f;  // 1/sqrt(192)*log2e

  const int nkb = qt + 1;
  const int q0w = qt * 64 + wq * 32;
  const int qlane = q0w + l31;

  // Q^T B-fragments from global: lane holds q = qlane, d = c*16 + hl*8 + i
  short8 qf[12];
#pragma unroll
  for (int c = 0; c < 12; c++)
    qf[c] = *(const short8*)&Qp[(size_t)qlane * HEAD_DIM + c * 16 + hl * 8];

  f32x16 oacc[6];
#pragma unroll
  for (int d = 0; d < 6; d++) oacc[d] = 0.f;
  float m = -3.0e38f, lsum = 0.f;

  short8 kr[6], vr[6];
  load_kv_regs(Kp, Vp, 0, w, lane, kr, vr);

  for (int kb = 0; kb < nkb; kb++) {
    const int kbase = kb * 64;

    // ---- staging phase: prev readers done -> write regs -> issue next loads ----
    asm volatile("" ::: "memory");
    __builtin_amdgcn_s_barrier();          // all waves done reading LDS tile kb-1
    asm volatile("" ::: "memory");
    write_kv_lds(Ks, Vs, w, lane, kr, vr); // waits on tile-kb loads (compiler vmcnt)
    if (kb + 1 < nkb)
      load_kv_regs(Kp, Vp, kbase + 64, w, lane, kr, vr);  // in flight during compute
    asm volatile("s_waitcnt lgkmcnt(0)" ::: "memory");    // own ds_writes done
    __builtin_amdgcn_sched_barrier(0);
    __builtin_amdgcn_s_barrier();          // LDS tile kb visible to all
    asm volatile("" ::: "memory");

    if (kbase + wk * 32 <= q0w + 31) {  // wave-uniform skip
      // S^T[32k][32q] = K * Q^T  (lane: q = l31; k in regs)
      f32x16 sacc = 0.f;
      const int krow = wk * 32 + l31;
      const int krb = krow * 192;
      const int kswz = (krow & 7) << 3;
      __builtin_amdgcn_s_setprio(1);
#pragma unroll
      for (int c = 0; c < 12; c++) {
        short8 kf = *(const short8*)&Ks[krb + ((c * 16 + hl * 8) ^ kswz)];
        sacc = __builtin_amdgcn_mfma_f32_32x32x16_bf16(kf, qf[c], sacc, 0, 0, 0);
      }
      __builtin_amdgcn_s_setprio(0);

      // in-lane softmax over this wave's 32-k slice
      float s[16];
      const bool need_mask = (kbase + wk * 32 + 31) > q0w;
      const int kb0 = kbase + wk * 32 + 4 * hl;
#pragma unroll
      for (int r = 0; r < 16; r++) {
        float v = sacc[r] * scale2;
        if (need_mask) {
          int kg = kb0 + (r & 3) + 8 * (r >> 2);
          if (kg > qlane) v = -3.0e38f;
        }
        s[r] = v;
      }
      float mx = s[0];
#pragma unroll
      for (int r = 1; r < 16; r++) mx = fmaxf(mx, s[r]);
      mx = fmaxf(mx, __shfl_xor(mx, 32, 64));
      if (!__all(mx <= m + 8.0f)) {  // defer-max
        float mn = fmaxf(m, mx);
        float al = fexp2(m - mn);
        m = mn;
        lsum *= al;
#pragma unroll
        for (int d = 0; d < 6; d++) oacc[d] *= al;
      }
      float pr[16];
      float rs = 0.f;
#pragma unroll
      for (int r = 0; r < 16; r++) {
        pr[r] = fexp2(s[r] - m);
        rs += pr[r];
      }
      rs += __shfl_xor(rs, 32, 64);
      lsum += rs;

      // pack P to bf16 pairs, exchange halves, build PV B-frags
      unsigned pk[8], ex[8];
#pragma unroll
      for (int j = 0; j < 8; j++) {
        unsigned r0;
        asm("v_cvt_pk_bf16_f32 %0, %1, %2" : "=v"(r0) : "v"(pr[2 * j]), "v"(pr[2 * j + 1]));
        pk[j] = r0;
      }
#pragma unroll
      for (int j = 0; j < 8; j++) ex[j] = __shfl_xor((int)pk[j], 32, 64);
      union { unsigned u[4]; short8 s8; } f0, f1;
      f0.u[0] = hl ? ex[2] : pk[0];
      f0.u[1] = hl ? ex[3] : pk[1];
      f0.u[2] = hl ? pk[2] : ex[0];
      f0.u[3] = hl ? pk[3] : ex[1];
      f1.u[0] = hl ? ex[6] : pk[4];
      f1.u[1] = hl ? ex[7] : pk[5];
      f1.u[2] = hl ? pk[6] : ex[4];
      f1.u[3] = hl ? pk[7] : ex[5];

      // O^T[32d][32q] += V^T * P^T   (lane: q = l31 -> alpha/l per-lane)
      __builtin_amdgcn_s_setprio(1);
#pragma unroll
      for (int db = 0; db < 6; db++) {
        const int vrow = db * 32 + l31;
        const int vrb = vrow * 64;
        const int vswz = (vrow & 7) << 3;
        short8 va = *(const short8*)&Vs[vrb + ((wk * 32 + hl * 8) ^ vswz)];
        oacc[db] = __builtin_amdgcn_mfma_f32_32x32x16_bf16(va, f0.s8, oacc[db], 0, 0, 0);
        short8 vb = *(const short8*)&Vs[vrb + ((wk * 32 + 16 + hl * 8) ^ vswz)];
        oacc[db] = __builtin_amdgcn_mfma_f32_32x32x16_bf16(vb, f1.s8, oacc[db], 0, 0, 0);
      }
      __builtin_amdgcn_s_setprio(0);
    }
  }

  // ---- k-split merge (waves wk=1 -> wk=0) + epilogue ----
  __syncthreads();
  if (wk == 1) {
    if (lane < 32) {
      mlbuf[wq * 64 + lane] = m;
      mlbuf[wq * 64 + 32 + lane] = lsum;
    }
#pragma unroll
    for (int db = 0; db < 6; db++)
#pragma unroll
      for (int g = 0; g < 4; g++) {
        int d = db * 32 + 8 * g + 4 * hl;
        f32x4 vv;
        vv[0] = oacc[db][4 * g];
        vv[1] = oacc[db][4 * g + 1];
        vv[2] = oacc[db][4 * g + 2];
        vv[3] = oacc[db][4 * g + 3];
        *(f32x4*)&obuf[(wq * 32 + l31) * 192 + (d ^ ((l31 & 7) << 2))] = vv;
      }
  }
  __syncthreads();
  if (wk == 0) {
    float m1 = mlbuf[wq * 64 + l31];
    float l1 = mlbuf[wq * 64 + 32 + l31];
    float ms = fmaxf(m, m1);
    float a0 = fexp2(m - ms), a1 = fexp2(m1 - ms);
    float lt = lsum * a0 + l1 * a1;
    float rl = 1.0f / lt;
#pragma unroll
    for (int db = 0; db < 6; db++)
#pragma unroll
      for (int g = 0; g < 4; g++) {
        int d = db * 32 + 8 * g + 4 * hl;
        f32x4 rd = *(const f32x4*)&obuf[(wq * 32 + l31) * 192 + (d ^ ((l31 & 7) << 2))];
        u16x4 pkk;
#pragma unroll
        for (int r2 = 0; r2 < 4; r2++) {
          float v = (oacc[db][4 * g + r2] * a0 + rd[r2] * a1) * rl;
          pkk[r2] = (unsigned short)f2bf(v);
        }
        *(u16x4*)&ctx[((size_t)b * SEQ + qlane) * D_MODEL + head * HEAD_DIM + d] = pkk;
      }
  }
}

// ---------------- launch ----------------
extern "C" void kernel_launch(void* const* d_in, const int* in_sizes, int n_in,
                              void* d_out, int out_size, void* d_ws, size_t ws_size,
                              hipStream_t stream) {
  const float* X  = (const float*)d_in[0];
  const float* Wq = (const float*)d_in[1];
  const float* bq = (const float*)d_in[2];
  const float* Wk = (const float*)d_in[3];
  const float* bk = (const float*)d_in[4];
  const float* Wv = (const float*)d_in[5];
  const float* bv = (const float*)d_in[6];
  const float* Wo = (const float*)d_in[7];
  const float* bo = (const float*)d_in[8];

  char* ws = (char*)d_ws;
  const size_t XB = (size_t)M_ROWS * D_MODEL * 2;
  const size_t WQKV = (size_t)3 * D_MODEL * D_MODEL * 2;
  const size_t WB = (size_t)D_MODEL * D_MODEL * 2;

  short* Xb    = (short*)(ws);
  short* Wqkvt = (short*)(ws + XB);
  short* Wot   = (short*)(ws + XB + WQKV);
  float* bqkv  = (float*)(ws + XB + WQKV + WB);
  short* Qb    = (short*)(ws + XB + WQKV + WB + 12288);
  short* Kb    = (short*)(ws + XB + WQKV + WB + 12288 + XB);
  short* Vtb   = (short*)(ws + XB + WQKV + WB + 12288 + 2 * XB);
  short* Cb    = (short*)(ws + XB + WQKV + WB + 12288 + 3 * XB);

  const int n8x = M_ROWS * D_MODEL / 8;
  cast_kernel<<<(n8x + 255) / 256, 256, 0, stream>>>(X, Xb, n8x);
  dim3 tg(24, 24);
  wtrans<<<tg, 256, 0, stream>>>(Wq, Wqkvt);
  wtrans<<<tg, 256, 0, stream>>>(Wk, Wqkvt + (size_t)768 * 768);
  wtrans<<<tg, 256, 0, stream>>>(Wv, Wqkvt + (size_t)2 * 768 * 768);
  wtrans<<<tg, 256, 0, stream>>>(Wo, Wot);
  bias_concat<<<9, 256, 0, stream>>>(bq, bk, bv, bqkv);

  gemm_bf16<1><<<dim3(M_ROWS / 128, 2304 / 128), 256, 0, stream>>>(
      Xb, Wqkvt, bqkv, Qb, Kb, Vtb, nullptr, 2304);

  attn_kernel<<<512, 256, 0, stream>>>(Qb, Kb, Vtb, Cb);

  gemm_bf16<0><<<dim3(M_ROWS / 128, 768 / 128), 256, 0, stream>>>(
      Cb, Wot, bo, nullptr, nullptr, nullptr, (float*)d_out, 768);
}

// Round 7
// 150.078 us; speedup vs baseline: 1.1787x; 1.1787x over previous
//
#include <hip/hip_runtime.h>
#include <hip/hip_bf16.h>
#include <cstddef>

typedef __attribute__((ext_vector_type(8))) short short8;
typedef __attribute__((ext_vector_type(4))) float f32x4;
typedef __attribute__((ext_vector_type(16))) float f32x16;
typedef __attribute__((ext_vector_type(4))) unsigned short u16x4;

#define D_MODEL 768
#define N_HEADS 4
#define HEAD_DIM 192
#define BATCH 4
#define SEQ 2048
#define M_ROWS (BATCH*SEQ)

__device__ __forceinline__ short f2bf(float f) {
  union { float f; unsigned u; } v; v.f = f;
  unsigned r = v.u + 0x7FFFu + ((v.u >> 16) & 1u);
  return (short)(r >> 16);
}

__device__ __forceinline__ float fexp2(float x) {
  return __builtin_amdgcn_exp2f(x);
}

__device__ __forceinline__ void gl_lds16(const void* g, void* l) {
  __builtin_amdgcn_global_load_lds(
      (const __attribute__((address_space(1))) void*)g,
      (__attribute__((address_space(3))) void*)l, 16, 0, 0);
}

// ---------------- cast fp32 -> bf16, 8 elems/thread ----------------
__global__ __launch_bounds__(256) void cast_kernel(const float* __restrict__ src,
                                                   short* __restrict__ dst, int n8) {
  int i = blockIdx.x * 256 + threadIdx.x;
  if (i >= n8) return;
  const float4* s = (const float4*)src;
  float4 a = s[2 * i], b = s[2 * i + 1];
  short8 o;
  o[0] = f2bf(a.x); o[1] = f2bf(a.y); o[2] = f2bf(a.z); o[3] = f2bf(a.w);
  o[4] = f2bf(b.x); o[5] = f2bf(b.y); o[6] = f2bf(b.z); o[7] = f2bf(b.w);
  *(short8*)(dst + (size_t)i * 8) = o;
}

// ---------------- transpose-cast W[k][n] f32 -> Wt[n][k] bf16 ----------------
__global__ __launch_bounds__(256) void wtrans(const float* __restrict__ W,
                                              short* __restrict__ Wt) {
  __shared__ float tile[32][33];
  int k0 = blockIdx.x * 32, n0 = blockIdx.y * 32;
  int tc = threadIdx.x & 31, tr = threadIdx.x >> 5;
#pragma unroll
  for (int i = 0; i < 4; i++)
    tile[tr + i * 8][tc] = W[(size_t)(k0 + tr + i * 8) * D_MODEL + n0 + tc];
  __syncthreads();
#pragma unroll
  for (int i = 0; i < 4; i++)
    Wt[(size_t)(n0 + tr + i * 8) * D_MODEL + k0 + tc] = f2bf(tile[tc][tr + i * 8]);
}

__global__ __launch_bounds__(256) void bias_concat(const float* __restrict__ a,
                                                   const float* __restrict__ b,
                                                   const float* __restrict__ c,
                                                   float* __restrict__ dst) {
  int i = blockIdx.x * 256 + threadIdx.x;
  if (i >= 3 * D_MODEL) return;
  float v = i < 768 ? a[i] : (i < 1536 ? b[i - 768] : c[i - 1536]);
  dst[i] = v;
}

// ---------------- bf16 MFMA GEMM, 128x128 tile, BK=64, global_load_lds ----------------
template <int MODE>
__global__ __launch_bounds__(256, 4) void gemm_bf16(const short* __restrict__ A,
                                                    const short* __restrict__ Wt,
                                                    const float* __restrict__ bias,
                                                    short* __restrict__ oQ,
                                                    short* __restrict__ oK,
                                                    short* __restrict__ oV,
                                                    float* __restrict__ oF, int N) {
  __shared__ short As[128 * 64];
  __shared__ short Bs[128 * 64];
  const int K = 768;
  const int m0 = blockIdx.x * 128, n0 = blockIdx.y * 128;
  const int t = threadIdx.x, lane = t & 63, w = t >> 6;
  const int wr = w >> 1, wc = w & 1, lr = lane & 15, lg = lane >> 4;

  f32x4 acc[4][4] = {};

  for (int k0 = 0; k0 < K; k0 += 64) {
#pragma unroll
    for (int i = 0; i < 4; i++) {
      int id = w * 4 + i;
      int row = id * 8 + (lane >> 3);
      int cc = (lane & 7) ^ (row & 7);
      gl_lds16(A + (size_t)(m0 + row) * K + k0 + cc * 8, As + id * 512);
      gl_lds16(Wt + (size_t)(n0 + row) * K + k0 + cc * 8, Bs + id * 512);
    }
    __syncthreads();
#pragma unroll
    for (int kb = 0; kb < 2; kb++) {
      short8 a[4], b[4];
#pragma unroll
      for (int m = 0; m < 4; m++) {
        int row = wr * 64 + m * 16 + lr;
        a[m] = *(const short8*)&As[row * 64 + (((kb * 4 + lg) ^ (row & 7)) << 3)];
      }
#pragma unroll
      for (int n = 0; n < 4; n++) {
        int row = wc * 64 + n * 16 + lr;
        b[n] = *(const short8*)&Bs[row * 64 + (((kb * 4 + lg) ^ (row & 7)) << 3)];
      }
#pragma unroll
      for (int m = 0; m < 4; m++)
#pragma unroll
        for (int n = 0; n < 4; n++)
          acc[m][n] = __builtin_amdgcn_mfma_f32_16x16x32_bf16(a[m], b[n], acc[m][n], 0, 0, 0);
    }
    __syncthreads();
  }

  if (MODE == 0) {
#pragma unroll
    for (int m = 0; m < 4; m++)
#pragma unroll
      for (int n = 0; n < 4; n++) {
        int col = n0 + wc * 64 + n * 16 + lr;
        float bv = bias[col];
#pragma unroll
        for (int r = 0; r < 4; r++) {
          int row = m0 + wr * 64 + m * 16 + lg * 4 + r;
          oF[(size_t)row * N + col] = acc[m][n][r] + bv;
        }
      }
  } else {
    const int bb = m0 >> 11;
#pragma unroll
    for (int m = 0; m < 4; m++) {
      int s0 = (m0 & (SEQ - 1)) + wr * 64 + m * 16 + lg * 4;
#pragma unroll
      for (int n = 0; n < 4; n++) {
        int col = n0 + wc * 64 + n * 16 + lr;
        int seg = col / 768;
        int d = col - seg * 768;
        int h = d / HEAD_DIM, dd = d - h * HEAD_DIM;
        int bh = bb * N_HEADS + h;
        float bv = bias[col];
        if (seg < 2) {
          short* dst = seg == 0 ? oQ : oK;
#pragma unroll
          for (int r = 0; r < 4; r++)
            dst[((size_t)bh * SEQ + s0 + r) * HEAD_DIM + dd] = f2bf(acc[m][n][r] + bv);
        } else {
          u16x4 pk;
#pragma unroll
          for (int r = 0; r < 4; r++) pk[r] = (unsigned short)f2bf(acc[m][n][r] + bv);
          *(u16x4*)&oV[((size_t)bh * HEAD_DIM + dd) * SEQ + s0] = pk;
        }
      }
    }
  }
}

// ---------------- attention staging helpers (gl_lds, no extra VGPRs) ----------------
__device__ __forceinline__ void stage_K(const short* Kp, int kbase, short* KsB,
                                        int w, int lane) {
#pragma unroll
  for (int i = 0; i < 6; i++) {
    int id = w * 6 + i;
    int o16 = id * 64 + lane;
    int row = o16 / 24, cc = (o16 - row * 24) ^ (row & 7);
    gl_lds16(Kp + (size_t)(kbase + row) * HEAD_DIM + cc * 8, KsB + id * 512);
  }
}

__device__ __forceinline__ void stage_V(const short* Vp, int kbase, short* VsB,
                                        int w, int lane) {
#pragma unroll
  for (int i = 0; i < 6; i++) {
    int id = w * 6 + i;
    int o16 = id * 64 + lane;
    int row = o16 >> 3, cc = (o16 & 7) ^ (row & 7);
    gl_lds16(Vp + (size_t)row * SEQ + kbase + cc * 8, VsB + id * 512);
  }
}

// ---------------- flash causal attention: 32x32 frags, swapped QK^T ----------------
// 512 blocks (one 64-row q-tile each), 4 waves = 2 q-split x 2 k-split.
// K double-buffered + V single-buffered in LDS (72KB) -> 2 blocks/CU.
// Counted vmcnt keeps V-stage and next-K-stage in flight under compute.
// Q,K: [bh][s][192]; V: [bh][192][s]; ctx: bf16 [b][s][768]
__global__ __launch_bounds__(256, 2) void attn_kernel(const short* __restrict__ Q,
                                                      const short* __restrict__ Kg,
                                                      const short* __restrict__ Vt,
                                                      short* __restrict__ ctx) {
  __shared__ short smem[2 * 64 * 192 + 192 * 64];  // K dbuf | V (73728 B)
  __shared__ float mlbuf[128];
  short* Kbuf0 = smem;
  short* Kbuf1 = smem + 64 * 192;
  short* Vs = smem + 2 * 64 * 192;
  float* obuf = (float*)smem;  // merge buffer, reuses region after k-loop

  // LPT pairing: first 256 blocks get qt 31..16, second 256 get qt 0..15
  const int i = blockIdx.x;
  int bh, qt;
  if (i < 256) { bh = i & 15; qt = 31 - (i >> 4); }
  else         { int j = i - 256; bh = j & 15; qt = j >> 4; }

  const int b = bh >> 2, head = bh & 3;
  const short* Qp = Q + (size_t)bh * SEQ * HEAD_DIM;
  const short* Kp = Kg + (size_t)bh * SEQ * HEAD_DIM;
  const short* Vp = Vt + (size_t)bh * HEAD_DIM * SEQ;
  const int t = threadIdx.x, lane = t & 63, w = t >> 6;
  const int wq = w >> 1, wk = w & 1;
  const int l31 = lane & 31, hl = lane >> 5;
  const float scale2 = 0.07216878364870322f * 1.4426950408889634f;  // 1/sqrt(192)*log2e

  const int nkb = qt + 1;
  const int q0w = qt * 64 + wq * 32;
  const int qlane = q0w + l31;

  // Q^T B-fragments from global: lane holds q = qlane, d = c*16 + hl*8 + i
  short8 qf[12];
#pragma unroll
  for (int c = 0; c < 12; c++)
    qf[c] = *(const short8*)&Qp[(size_t)qlane * HEAD_DIM + c * 16 + hl * 8];

  f32x16 oacc[6];
#pragma unroll
  for (int d = 0; d < 6; d++) oacc[d] = 0.f;
  float m = -3.0e38f, lsum = 0.f;

  stage_K(Kp, 0, Kbuf0, w, lane);  // 6 loads in flight

  for (int kb = 0; kb < nkb; kb++) {
    const int cur = kb & 1;
    const int kbase = kb * 64;
    short* Kc = cur ? Kbuf1 : Kbuf0;
    const bool has_next = (kb + 1 < nkb);

    // issue V[kb] stage (V[kb-1] readers done: end-of-prev-iter barrier)
    stage_V(Vp, kbase, Vs, w, lane);
    if (has_next) {
      stage_K(Kp, kbase + 64, cur ? Kbuf0 : Kbuf1, w, lane);
      asm volatile("s_waitcnt vmcnt(12)" ::: "memory");  // K[kb] done; V+K' in flight
    } else {
      asm volatile("s_waitcnt vmcnt(6)" ::: "memory");   // K[kb] done; V in flight
    }
    __builtin_amdgcn_s_barrier();  // K[kb] visible to all waves
    asm volatile("" ::: "memory");

    const bool active = (kbase + wk * 32 <= q0w + 31);
    unsigned pk[8], ex[8];
    float pr[16];

    if (active) {
      // S^T[32k][32q] = K * Q^T  (lane: q = l31; k in regs)
      f32x16 sacc = 0.f;
      const int krow = wk * 32 + l31;
      const int krb = krow * 192;
      const int kswz = (krow & 7) << 3;
      __builtin_amdgcn_s_setprio(1);
#pragma unroll
      for (int c = 0; c < 12; c++) {
        short8 kf = *(const short8*)&Kc[krb + ((c * 16 + hl * 8) ^ kswz)];
        sacc = __builtin_amdgcn_mfma_f32_32x32x16_bf16(kf, qf[c], sacc, 0, 0, 0);
      }
      __builtin_amdgcn_s_setprio(0);

      // in-lane softmax over this wave's 32-k slice
      float s[16];
      const bool need_mask = (kbase + wk * 32 + 31) > q0w;
      const int kb0 = kbase + wk * 32 + 4 * hl;
#pragma unroll
      for (int r = 0; r < 16; r++) {
        float v = sacc[r] * scale2;
        if (need_mask) {
          int kg = kb0 + (r & 3) + 8 * (r >> 2);
          if (kg > qlane) v = -3.0e38f;
        }
        s[r] = v;
      }
      float mx = s[0];
#pragma unroll
      for (int r = 1; r < 16; r++) mx = fmaxf(mx, s[r]);
      mx = fmaxf(mx, __shfl_xor(mx, 32, 64));
      if (!__all(mx <= m + 8.0f)) {  // defer-max
        float mn = fmaxf(m, mx);
        float al = fexp2(m - mn);
        m = mn;
        lsum *= al;
#pragma unroll
        for (int d = 0; d < 6; d++) oacc[d] *= al;
      }
      float rs = 0.f;
#pragma unroll
      for (int r = 0; r < 16; r++) {
        pr[r] = fexp2(s[r] - m);
        rs += pr[r];
      }
      rs += __shfl_xor(rs, 32, 64);
      lsum += rs;

      // pack P to bf16 pairs
#pragma unroll
      for (int j = 0; j < 8; j++) {
        unsigned r0;
        asm("v_cvt_pk_bf16_f32 %0, %1, %2" : "=v"(r0) : "v"(pr[2 * j]), "v"(pr[2 * j + 1]));
        pk[j] = r0;
      }
#pragma unroll
      for (int j = 0; j < 8; j++) ex[j] = __shfl_xor((int)pk[j], 32, 64);
    }

    // V[kb] ready (keep next-K in flight)
    if (has_next) asm volatile("s_waitcnt vmcnt(6)" ::: "memory");
    else          asm volatile("s_waitcnt vmcnt(0)" ::: "memory");
    __builtin_amdgcn_s_barrier();  // V visible to all waves
    asm volatile("" ::: "memory");

    if (active) {
      union { unsigned u[4]; short8 s8; } f0, f1;
      f0.u[0] = hl ? ex[2] : pk[0];
      f0.u[1] = hl ? ex[3] : pk[1];
      f0.u[2] = hl ? pk[2] : ex[0];
      f0.u[3] = hl ? pk[3] : ex[1];
      f1.u[0] = hl ? ex[6] : pk[4];
      f1.u[1] = hl ? ex[7] : pk[5];
      f1.u[2] = hl ? pk[6] : ex[4];
      f1.u[3] = hl ? pk[7] : ex[5];

      // O^T[32d][32q] += V^T * P^T   (lane: q = l31 -> alpha/l per-lane)
      __builtin_amdgcn_s_setprio(1);
#pragma unroll
      for (int db = 0; db < 6; db++) {
        const int vrow = db * 32 + l31;
        const int vrb = vrow * 64;
        const int vswz = (vrow & 7) << 3;
        short8 va = *(const short8*)&Vs[vrb + ((wk * 32 + hl * 8) ^ vswz)];
        oacc[db] = __builtin_amdgcn_mfma_f32_32x32x16_bf16(va, f0.s8, oacc[db], 0, 0, 0);
        short8 vb = *(const short8*)&Vs[vrb + ((wk * 32 + 16 + hl * 8) ^ vswz)];
        oacc[db] = __builtin_amdgcn_mfma_f32_32x32x16_bf16(vb, f1.s8, oacc[db], 0, 0, 0);
      }
      __builtin_amdgcn_s_setprio(0);
    }
    asm volatile("" ::: "memory");
    __builtin_amdgcn_s_barrier();  // all V/K readers done before next overwrite
  }

  // ---- k-split merge (waves wk=1 -> wk=0) + epilogue ----
  __syncthreads();
  if (wk == 1) {
    if (lane < 32) {
      mlbuf[wq * 64 + lane] = m;
      mlbuf[wq * 64 + 32 + lane] = lsum;
    }
#pragma unroll
    for (int db = 0; db < 6; db++)
#pragma unroll
      for (int g = 0; g < 4; g++) {
        int d = db * 32 + 8 * g + 4 * hl;
        f32x4 vv;
        vv[0] = oacc[db][4 * g];
        vv[1] = oacc[db][4 * g + 1];
        vv[2] = oacc[db][4 * g + 2];
        vv[3] = oacc[db][4 * g + 3];
        *(f32x4*)&obuf[(wq * 32 + l31) * 192 + (d ^ ((l31 & 7) << 2))] = vv;
      }
  }
  __syncthreads();
  if (wk == 0) {
    float m1 = mlbuf[wq * 64 + l31];
    float l1 = mlbuf[wq * 64 + 32 + l31];
    float ms = fmaxf(m, m1);
    float a0 = fexp2(m - ms), a1 = fexp2(m1 - ms);
    float lt = lsum * a0 + l1 * a1;
    float rl = 1.0f / lt;
#pragma unroll
    for (int db = 0; db < 6; db++)
#pragma unroll
      for (int g = 0; g < 4; g++) {
        int d = db * 32 + 8 * g + 4 * hl;
        f32x4 rd = *(const f32x4*)&obuf[(wq * 32 + l31) * 192 + (d ^ ((l31 & 7) << 2))];
        u16x4 pkk;
#pragma unroll
        for (int r2 = 0; r2 < 4; r2++) {
          float v = (oacc[db][4 * g + r2] * a0 + rd[r2] * a1) * rl;
          pkk[r2] = (unsigned short)f2bf(v);
        }
        *(u16x4*)&ctx[((size_t)b * SEQ + qlane) * D_MODEL + head * HEAD_DIM + d] = pkk;
      }
  }
}

// ---------------- launch ----------------
extern "C" void kernel_launch(void* const* d_in, const int* in_sizes, int n_in,
                              void* d_out, int out_size, void* d_ws, size_t ws_size,
                              hipStream_t stream) {
  const float* X  = (const float*)d_in[0];
  const float* Wq = (const float*)d_in[1];
  const float* bq = (const float*)d_in[2];
  const float* Wk = (const float*)d_in[3];
  const float* bk = (const float*)d_in[4];
  const float* Wv = (const float*)d_in[5];
  const float* bv = (const float*)d_in[6];
  const float* Wo = (const float*)d_in[7];
  const float* bo = (const float*)d_in[8];

  char* ws = (char*)d_ws;
  const size_t XB = (size_t)M_ROWS * D_MODEL * 2;
  const size_t WQKV = (size_t)3 * D_MODEL * D_MODEL * 2;
  const size_t WB = (size_t)D_MODEL * D_MODEL * 2;

  short* Xb    = (short*)(ws);
  short* Wqkvt = (short*)(ws + XB);
  short* Wot   = (short*)(ws + XB + WQKV);
  float* bqkv  = (float*)(ws + XB + WQKV + WB);
  short* Qb    = (short*)(ws + XB + WQKV + WB + 12288);
  short* Kb    = (short*)(ws + XB + WQKV + WB + 12288 + XB);
  short* Vtb   = (short*)(ws + XB + WQKV + WB + 12288 + 2 * XB);
  short* Cb    = (short*)(ws + XB + WQKV + WB + 12288 + 3 * XB);

  const int n8x = M_ROWS * D_MODEL / 8;
  cast_kernel<<<(n8x + 255) / 256, 256, 0, stream>>>(X, Xb, n8x);
  dim3 tg(24, 24);
  wtrans<<<tg, 256, 0, stream>>>(Wq, Wqkvt);
  wtrans<<<tg, 256, 0, stream>>>(Wk, Wqkvt + (size_t)768 * 768);
  wtrans<<<tg, 256, 0, stream>>>(Wv, Wqkvt + (size_t)2 * 768 * 768);
  wtrans<<<tg, 256, 0, stream>>>(Wo, Wot);
  bias_concat<<<9, 256, 0, stream>>>(bq, bk, bv, bqkv);

  gemm_bf16<1><<<dim3(M_ROWS / 128, 2304 / 128), 256, 0, stream>>>(
      Xb, Wqkvt, bqkv, Qb, Kb, Vtb, nullptr, 2304);

  attn_kernel<<<512, 256, 0, stream>>>(Qb, Kb, Vtb, Cb);

  gemm_bf16<0><<<dim3(M_ROWS / 128, 768 / 128), 256, 0, stream>>>(
      Cb, Wot, bo, nullptr, nullptr, nullptr, (float*)d_out, 768);
}

// Round 8
// 139.913 us; speedup vs baseline: 1.2643x; 1.0727x over previous
//
#include <hip/hip_runtime.h>
#include <hip/hip_bf16.h>
#include <cstddef>

typedef __attribute__((ext_vector_type(8))) short short8;
typedef __attribute__((ext_vector_type(4))) float f32x4;
typedef __attribute__((ext_vector_type(16))) float f32x16;
typedef __attribute__((ext_vector_type(4))) unsigned short u16x4;

#define D_MODEL 768
#define N_HEADS 4
#define HEAD_DIM 192
#define BATCH 4
#define SEQ 2048
#define M_ROWS (BATCH*SEQ)

__device__ __forceinline__ short f2bf(float f) {
  union { float f; unsigned u; } v; v.f = f;
  unsigned r = v.u + 0x7FFFu + ((v.u >> 16) & 1u);
  return (short)(r >> 16);
}

__device__ __forceinline__ float fexp2(float x) {
  return __builtin_amdgcn_exp2f(x);
}

__device__ __forceinline__ void gl_lds16(const void* g, void* l) {
  __builtin_amdgcn_global_load_lds(
      (const __attribute__((address_space(1))) void*)g,
      (__attribute__((address_space(3))) void*)l, 16, 0, 0);
}

// ---------------- cast fp32 -> bf16, 8 elems/thread ----------------
__global__ __launch_bounds__(256) void cast_kernel(const float* __restrict__ src,
                                                   short* __restrict__ dst, int n8) {
  int i = blockIdx.x * 256 + threadIdx.x;
  if (i >= n8) return;
  const float4* s = (const float4*)src;
  float4 a = s[2 * i], b = s[2 * i + 1];
  short8 o;
  o[0] = f2bf(a.x); o[1] = f2bf(a.y); o[2] = f2bf(a.z); o[3] = f2bf(a.w);
  o[4] = f2bf(b.x); o[5] = f2bf(b.y); o[6] = f2bf(b.z); o[7] = f2bf(b.w);
  *(short8*)(dst + (size_t)i * 8) = o;
}

// ---------------- transpose-cast 4 weight mats in one launch ----------------
// z in [0,4): Wq,Wk,Wv -> Wqkvt + z*768*768 ; z==3: Wo -> Wot
__global__ __launch_bounds__(256) void wtrans4(const float* __restrict__ W0,
                                               const float* __restrict__ W1,
                                               const float* __restrict__ W2,
                                               const float* __restrict__ W3,
                                               short* __restrict__ Wqkvt,
                                               short* __restrict__ Wot) {
  __shared__ float tile[32][33];
  int z = blockIdx.z;
  const float* W = z == 0 ? W0 : (z == 1 ? W1 : (z == 2 ? W2 : W3));
  short* Wt = z < 3 ? (Wqkvt + (size_t)z * 768 * 768) : Wot;
  int k0 = blockIdx.x * 32, n0 = blockIdx.y * 32;
  int tc = threadIdx.x & 31, tr = threadIdx.x >> 5;
#pragma unroll
  for (int i = 0; i < 4; i++)
    tile[tr + i * 8][tc] = W[(size_t)(k0 + tr + i * 8) * D_MODEL + n0 + tc];
  __syncthreads();
#pragma unroll
  for (int i = 0; i < 4; i++)
    Wt[(size_t)(n0 + tr + i * 8) * D_MODEL + k0 + tc] = f2bf(tile[tc][tr + i * 8]);
}

// ---------------- bf16 MFMA GEMM, 128x128 tile, BK=64, global_load_lds ----------------
// 1D grid with bijective XCD swizzle: each XCD owns contiguous bx panels x all by.
// MODE 1: QKV fused -> Q,K split-head [bh][s][d]; V transposed [bh][d][s]; bias = b0/b1/b2 by seg
// MODE 0: out fp32 [M][N] + bias b0
template <int MODE>
__global__ __launch_bounds__(256, 4) void gemm_bf16(const short* __restrict__ A,
                                                    const short* __restrict__ Wt,
                                                    const float* __restrict__ b0,
                                                    const float* __restrict__ b1,
                                                    const float* __restrict__ b2,
                                                    short* __restrict__ oQ,
                                                    short* __restrict__ oK,
                                                    short* __restrict__ oV,
                                                    float* __restrict__ oF,
                                                    int N, int NB) {
  __shared__ short As[128 * 64];
  __shared__ short Bs[128 * 64];
  const int K = 768;
  // XCD swizzle: nwg%8==0 guaranteed by launch; xcd gets contiguous chunk
  const int lid = blockIdx.x;
  const int nlid = (lid & 7) * ((int)gridDim.x >> 3) + (lid >> 3);
  const int m0 = (nlid / NB) * 128, n0 = (nlid % NB) * 128;
  const int t = threadIdx.x, lane = t & 63, w = t >> 6;
  const int wr = w >> 1, wc = w & 1, lr = lane & 15, lg = lane >> 4;

  f32x4 acc[4][4] = {};

  for (int k0 = 0; k0 < K; k0 += 64) {
#pragma unroll
    for (int i = 0; i < 4; i++) {
      int id = w * 4 + i;
      int row = id * 8 + (lane >> 3);
      int cc = (lane & 7) ^ (row & 7);
      gl_lds16(A + (size_t)(m0 + row) * K + k0 + cc * 8, As + id * 512);
      gl_lds16(Wt + (size_t)(n0 + row) * K + k0 + cc * 8, Bs + id * 512);
    }
    __syncthreads();
#pragma unroll
    for (int kb = 0; kb < 2; kb++) {
      short8 a[4], b[4];
#pragma unroll
      for (int m = 0; m < 4; m++) {
        int row = wr * 64 + m * 16 + lr;
        a[m] = *(const short8*)&As[row * 64 + (((kb * 4 + lg) ^ (row & 7)) << 3)];
      }
#pragma unroll
      for (int n = 0; n < 4; n++) {
        int row = wc * 64 + n * 16 + lr;
        b[n] = *(const short8*)&Bs[row * 64 + (((kb * 4 + lg) ^ (row & 7)) << 3)];
      }
#pragma unroll
      for (int m = 0; m < 4; m++)
#pragma unroll
        for (int n = 0; n < 4; n++)
          acc[m][n] = __builtin_amdgcn_mfma_f32_16x16x32_bf16(a[m], b[n], acc[m][n], 0, 0, 0);
    }
    __syncthreads();
  }

  if (MODE == 0) {
#pragma unroll
    for (int m = 0; m < 4; m++)
#pragma unroll
      for (int n = 0; n < 4; n++) {
        int col = n0 + wc * 64 + n * 16 + lr;
        float bv = b0[col];
#pragma unroll
        for (int r = 0; r < 4; r++) {
          int row = m0 + wr * 64 + m * 16 + lg * 4 + r;
          oF[(size_t)row * N + col] = acc[m][n][r] + bv;
        }
      }
  } else {
    const int bb = m0 >> 11;
#pragma unroll
    for (int m = 0; m < 4; m++) {
      int s0 = (m0 & (SEQ - 1)) + wr * 64 + m * 16 + lg * 4;
#pragma unroll
      for (int n = 0; n < 4; n++) {
        int col = n0 + wc * 64 + n * 16 + lr;
        int seg = col / 768;
        int d = col - seg * 768;
        int h = d / HEAD_DIM, dd = d - h * HEAD_DIM;
        int bh = bb * N_HEADS + h;
        float bv = (seg == 0 ? b0 : (seg == 1 ? b1 : b2))[d];
        if (seg < 2) {
          short* dst = seg == 0 ? oQ : oK;
#pragma unroll
          for (int r = 0; r < 4; r++)
            dst[((size_t)bh * SEQ + s0 + r) * HEAD_DIM + dd] = f2bf(acc[m][n][r] + bv);
        } else {
          u16x4 pk;
#pragma unroll
          for (int r = 0; r < 4; r++) pk[r] = (unsigned short)f2bf(acc[m][n][r] + bv);
          *(u16x4*)&oV[((size_t)bh * HEAD_DIM + dd) * SEQ + s0] = pk;
        }
      }
    }
  }
}

// ---------------- staging helper for attention (K + transposed V) ----------------
__device__ __forceinline__ void stage_kv(const short* Kp, const short* Vp, int kbase,
                                         short* KsB, short* VsB, int w, int lane) {
#pragma unroll
  for (int i = 0; i < 6; i++) {
    int id = w * 6 + i;
    int o16 = id * 64 + lane;
    int row = o16 / 24, cc0 = o16 - row * 24;
    int cc = cc0 ^ (row & 7);
    gl_lds16(Kp + (size_t)(kbase + row) * HEAD_DIM + cc * 8, KsB + id * 512);
  }
#pragma unroll
  for (int i = 0; i < 6; i++) {
    int id = w * 6 + i;
    int o16 = id * 64 + lane;
    int row = o16 >> 3, cc = (o16 & 7) ^ (row & 7);
    gl_lds16(Vp + (size_t)row * SEQ + kbase + cc * 8, VsB + id * 512);
  }
}

// ---------------- flash causal attention: 32x32 frags, swapped QK^T (R5 proven) ----------------
// 512 blocks (one 64-row q-tile each), 4 waves = 2 q-split x 2 k-split.
// Single-buffered K/V LDS (48KB) -> 2 blocks/CU, 2 waves/SIMD.
// Q,K: [bh][s][192]; V: [bh][192][s]; ctx: bf16 [b][s][768]
__global__ __launch_bounds__(256, 2) void attn_kernel(const short* __restrict__ Q,
                                                      const short* __restrict__ Kg,
                                                      const short* __restrict__ Vt,
                                                      short* __restrict__ ctx) {
  __shared__ short smem[64 * 192 + 192 * 64];  // K tile | V tile (49152 B)
  __shared__ float mlbuf[128];
  short* Ks = smem;
  short* Vs = smem + 64 * 192;
  float* obuf = (float*)smem;  // merge buffer, reuses K+V region after k-loop

  // LPT pairing: first 256 blocks get qt 31..16, second 256 get qt 0..15
  const int i = blockIdx.x;
  int bh, qt;
  if (i < 256) { bh = i & 15; qt = 31 - (i >> 4); }
  else         { int j = i - 256; bh = j & 15; qt = j >> 4; }

  const int b = bh >> 2, head = bh & 3;
  const short* Qp = Q + (size_t)bh * SEQ * HEAD_DIM;
  const short* Kp = Kg + (size_t)bh * SEQ * HEAD_DIM;
  const short* Vp = Vt + (size_t)bh * HEAD_DIM * SEQ;
  const int t = threadIdx.x, lane = t & 63, w = t >> 6;
  const int wq = w >> 1, wk = w & 1;
  const int l31 = lane & 31, hl = lane >> 5;
  const float scale2 = 0.07216878364870322f * 1.4426950408889634f;  // 1/sqrt(192)*log2e

  const int nkb = qt + 1;
  const int q0w = qt * 64 + wq * 32;
  const int qlane = q0w + l31;

  // Q^T B-fragments from global: lane holds q = qlane, d = c*16 + hl*8 + i
  short8 qf[12];
#pragma unroll
  for (int c = 0; c < 12; c++)
    qf[c] = *(const short8*)&Qp[(size_t)qlane * HEAD_DIM + c * 16 + hl * 8];

  f32x16 oacc[6];
#pragma unroll
  for (int d = 0; d < 6; d++) oacc[d] = 0.f;
  float m = -3.0e38f, lsum = 0.f;

  for (int kb = 0; kb < nkb; kb++) {
    const int kbase = kb * 64;
    stage_kv(Kp, Vp, kbase, Ks, Vs, w, lane);
    asm volatile("s_waitcnt vmcnt(0)" ::: "memory");
    __builtin_amdgcn_s_barrier();
    asm volatile("" ::: "memory");

    if (kbase + wk * 32 <= q0w + 31) {  // wave-uniform skip
      // S^T[32k][32q] = K * Q^T  (lane: q = l31; k in regs)
      f32x16 sacc = 0.f;
      const int krow = wk * 32 + l31;
      const int krb = krow * 192;
      const int kswz = (krow & 7) << 3;
      __builtin_amdgcn_s_setprio(1);
#pragma unroll
      for (int c = 0; c < 12; c++) {
        short8 kf = *(const short8*)&Ks[krb + ((c * 16 + hl * 8) ^ kswz)];
        sacc = __builtin_amdgcn_mfma_f32_32x32x16_bf16(kf, qf[c], sacc, 0, 0, 0);
      }
      __builtin_amdgcn_s_setprio(0);

      // in-lane softmax over this wave's 32-k slice
      float s[16];
      const bool need_mask = (kbase + wk * 32 + 31) > q0w;
      const int kb0 = kbase + wk * 32 + 4 * hl;
#pragma unroll
      for (int r = 0; r < 16; r++) {
        float v = sacc[r] * scale2;
        if (need_mask) {
          int kg = kb0 + (r & 3) + 8 * (r >> 2);
          if (kg > qlane) v = -3.0e38f;
        }
        s[r] = v;
      }
      float mx = s[0];
#pragma unroll
      for (int r = 1; r < 16; r++) mx = fmaxf(mx, s[r]);
      mx = fmaxf(mx, __shfl_xor(mx, 32, 64));
      if (!__all(mx <= m + 8.0f)) {  // defer-max
        float mn = fmaxf(m, mx);
        float al = fexp2(m - mn);
        m = mn;
        lsum *= al;
#pragma unroll
        for (int d = 0; d < 6; d++) oacc[d] *= al;
      }
      float pr[16];
      float rs = 0.f;
#pragma unroll
      for (int r = 0; r < 16; r++) {
        pr[r] = fexp2(s[r] - m);
        rs += pr[r];
      }
      rs += __shfl_xor(rs, 32, 64);
      lsum += rs;

      // pack P to bf16 pairs, exchange halves, build PV B-frags
      unsigned pk[8], ex[8];
#pragma unroll
      for (int j = 0; j < 8; j++) {
        unsigned r0;
        asm("v_cvt_pk_bf16_f32 %0, %1, %2" : "=v"(r0) : "v"(pr[2 * j]), "v"(pr[2 * j + 1]));
        pk[j] = r0;
      }
#pragma unroll
      for (int j = 0; j < 8; j++) ex[j] = __shfl_xor((int)pk[j], 32, 64);
      union { unsigned u[4]; short8 s8; } f0, f1;
      f0.u[0] = hl ? ex[2] : pk[0];
      f0.u[1] = hl ? ex[3] : pk[1];
      f0.u[2] = hl ? pk[2] : ex[0];
      f0.u[3] = hl ? pk[3] : ex[1];
      f1.u[0] = hl ? ex[6] : pk[4];
      f1.u[1] = hl ? ex[7] : pk[5];
      f1.u[2] = hl ? pk[6] : ex[4];
      f1.u[3] = hl ? pk[7] : ex[5];

      // O^T[32d][32q] += V^T * P^T   (lane: q = l31 -> alpha/l per-lane)
      __builtin_amdgcn_s_setprio(1);
#pragma unroll
      for (int db = 0; db < 6; db++) {
        const int vrow = db * 32 + l31;
        const int vrb = vrow * 64;
        const int vswz = (vrow & 7) << 3;
        short8 va = *(const short8*)&Vs[vrb + ((wk * 32 + hl * 8) ^ vswz)];
        oacc[db] = __builtin_amdgcn_mfma_f32_32x32x16_bf16(va, f0.s8, oacc[db], 0, 0, 0);
        short8 vb = *(const short8*)&Vs[vrb + ((wk * 32 + 16 + hl * 8) ^ vswz)];
        oacc[db] = __builtin_amdgcn_mfma_f32_32x32x16_bf16(vb, f1.s8, oacc[db], 0, 0, 0);
      }
      __builtin_amdgcn_s_setprio(0);
    }
    asm volatile("" ::: "memory");
    __builtin_amdgcn_s_barrier();  // protect buffers before next stage overwrites
  }

  // ---- k-split merge (waves wk=1 -> wk=0) + epilogue ----
  __syncthreads();
  if (wk == 1) {
    if (lane < 32) {
      mlbuf[wq * 64 + lane] = m;
      mlbuf[wq * 64 + 32 + lane] = lsum;
    }
#pragma unroll
    for (int db = 0; db < 6; db++)
#pragma unroll
      for (int g = 0; g < 4; g++) {
        int d = db * 32 + 8 * g + 4 * hl;
        f32x4 vv;
        vv[0] = oacc[db][4 * g];
        vv[1] = oacc[db][4 * g + 1];
        vv[2] = oacc[db][4 * g + 2];
        vv[3] = oacc[db][4 * g + 3];
        *(f32x4*)&obuf[(wq * 32 + l31) * 192 + (d ^ ((l31 & 7) << 2))] = vv;
      }
  }
  __syncthreads();
  if (wk == 0) {
    float m1 = mlbuf[wq * 64 + l31];
    float l1 = mlbuf[wq * 64 + 32 + l31];
    float ms = fmaxf(m, m1);
    float a0 = fexp2(m - ms), a1 = fexp2(m1 - ms);
    float lt = lsum * a0 + l1 * a1;
    float rl = 1.0f / lt;
#pragma unroll
    for (int db = 0; db < 6; db++)
#pragma unroll
      for (int g = 0; g < 4; g++) {
        int d = db * 32 + 8 * g + 4 * hl;
        f32x4 rd = *(const f32x4*)&obuf[(wq * 32 + l31) * 192 + (d ^ ((l31 & 7) << 2))];
        u16x4 pkk;
#pragma unroll
        for (int r2 = 0; r2 < 4; r2++) {
          float v = (oacc[db][4 * g + r2] * a0 + rd[r2] * a1) * rl;
          pkk[r2] = (unsigned short)f2bf(v);
        }
        *(u16x4*)&ctx[((size_t)b * SEQ + qlane) * D_MODEL + head * HEAD_DIM + d] = pkk;
      }
  }
}

// ---------------- launch ----------------
extern "C" void kernel_launch(void* const* d_in, const int* in_sizes, int n_in,
                              void* d_out, int out_size, void* d_ws, size_t ws_size,
                              hipStream_t stream) {
  const float* X  = (const float*)d_in[0];
  const float* Wq = (const float*)d_in[1];
  const float* bq = (const float*)d_in[2];
  const float* Wk = (const float*)d_in[3];
  const float* bk = (const float*)d_in[4];
  const float* Wv = (const float*)d_in[5];
  const float* bv = (const float*)d_in[6];
  const float* Wo = (const float*)d_in[7];
  const float* bo = (const float*)d_in[8];

  char* ws = (char*)d_ws;
  const size_t XB = (size_t)M_ROWS * D_MODEL * 2;
  const size_t WQKV = (size_t)3 * D_MODEL * D_MODEL * 2;
  const size_t WB = (size_t)D_MODEL * D_MODEL * 2;

  short* Xb    = (short*)(ws);
  short* Wqkvt = (short*)(ws + XB);
  short* Wot   = (short*)(ws + XB + WQKV);
  short* Qb    = (short*)(ws + XB + WQKV + WB + 12288);
  short* Kb    = (short*)(ws + XB + WQKV + WB + 12288 + XB);
  short* Vtb   = (short*)(ws + XB + WQKV + WB + 12288 + 2 * XB);
  short* Cb    = (short*)(ws + XB + WQKV + WB + 12288 + 3 * XB);

  const int n8x = M_ROWS * D_MODEL / 8;
  cast_kernel<<<(n8x + 255) / 256, 256, 0, stream>>>(X, Xb, n8x);
  wtrans4<<<dim3(24, 24, 4), 256, 0, stream>>>(Wq, Wk, Wv, Wo, Wqkvt, Wot);

  // QKV fused GEMM: M=8192, N=2304 -> grid 64*18=1152 (div by 8)
  gemm_bf16<1><<<1152, 256, 0, stream>>>(Xb, Wqkvt, bq, bk, bv,
                                         Qb, Kb, Vtb, nullptr, 2304, 18);

  attn_kernel<<<512, 256, 0, stream>>>(Qb, Kb, Vtb, Cb);

  // out GEMM: M=8192, N=768 -> grid 64*6=384 (div by 8)
  gemm_bf16<0><<<384, 256, 0, stream>>>(Cb, Wot, bo, bo, bo,
                                        nullptr, nullptr, nullptr, (float*)d_out, 768, 6);
}